// Round 17
// baseline (120.534 us; speedup 1.0000x reference)
//
#include <hip/hip_runtime.h>
#include <math.h>

#define N_NODES   100000
#define N_HEDGES  100000
#define N_INC     1000000
#define IN_DIM    128
#define SHIFT     7
#define BMASK     127
#define NBKT      782        // ceil(100000/128)
#define CAP       2048       // padded bucket capacity (max expected ~1500)
#define NBLD      64         // build chunks (1024 threads * 16 items)
#define GRID_BG   336        // 64 build + 272 gemm, XCD-interleaved
#define GEMM_TOT  272
#define NGRP      (GEMM_TOT * 32)
#define BT        1024

typedef unsigned int u32;

// ---------------------------------------------------------------------------
// fused: XCD-aware role interleave. Groups(8 blocks) 0..15 alternate
// build/gemm so every XCD holds both roles; groups 16+ are pure gemm.
// build: 16384 items/chunk (4 int4/thread, register ranks, L2-hot re-read),
// ONE packed dual-direction cursor atomic per bucket, ~21-item payload runs
// (4x less dirty-line write amplification than 245-chunk version).
__global__ void __launch_bounds__(BT)
fused_bg_kernel(const int* __restrict__ ei0, const int* __restrict__ ei1,
                const float* __restrict__ X, const float* __restrict__ W1,
                const float* __restrict__ b1, const float* __restrict__ W2,
                u32* __restrict__ gcur, u32* __restrict__ payload_n,
                u32* __restrict__ payload_h, float* __restrict__ cvec,
                float* __restrict__ Z)
{
    __shared__ int hA[NBKT], hB[NBKT];   // gemm branch reuses first 384 as floats
    int blk = blockIdx.x, t = threadIdx.x;

    int group = blk >> 3;                // groups of 8 (one block per XCD)
    int inb   = blk & 7;
    bool is_build = (group < 16) && ((group & 1) == 0);
    int rid = (group >> 1) * 8 + inb;    // build id 0..63
    int gemm_id = (group < 16) ? ((group >> 1) * 8 + inb)
                               : (64 + (group - 16) * 8 + inb);

    if (is_build) {
        // ---------------- build ----------------
        for (int i = t; i < NBKT; i += BT) { hA[i] = 0; hB[i] = 0; }
        __syncthreads();
        int base4 = rid * 4096;                  // int4 index base (16384 items)
        int rn[16], rh[16];
        #pragma unroll
        for (int k = 0; k < 4; ++k) {
            int i4 = base4 + k * 1024 + t;
            if (i4 * 4 < N_INC) {
                int4 n4 = ((const int4*)ei0)[i4];
                int4 h4 = ((const int4*)ei1)[i4];
                int nn[4] = {n4.x, n4.y, n4.z, n4.w};
                int hv[4] = {h4.x, h4.y, h4.z, h4.w};
                #pragma unroll
                for (int e = 0; e < 4; ++e) {
                    rn[k * 4 + e] = atomicAdd(&hA[nn[e] >> SHIFT], 1);
                    rh[k * 4 + e] = atomicAdd(&hB[hv[e] >> SHIFT], 1);
                }
            }
        }
        __syncthreads();
        // exchange: ONE packed atomic reserves space in BOTH directions
        for (int i = t; i < NBKT; i += BT) {
            int cn = hA[i], ch = hB[i];
            if (cn | ch) {
                u32 old = atomicAdd(&gcur[i * 16], (u32)cn | ((u32)ch << 16));
                hA[i] = i * CAP + (int)(old & 0xFFFFu);
                hB[i] = i * CAP + (int)(old >> 16);
            }
        }
        __syncthreads();
        // place: re-read ids (L2-hot), use register ranks
        #pragma unroll
        for (int k = 0; k < 4; ++k) {
            int i4 = base4 + k * 1024 + t;
            if (i4 * 4 < N_INC) {
                int4 n4 = ((const int4*)ei0)[i4];
                int4 h4 = ((const int4*)ei1)[i4];
                int nn[4] = {n4.x, n4.y, n4.z, n4.w};
                int hv[4] = {h4.x, h4.y, h4.z, h4.w};
                #pragma unroll
                for (int e = 0; e < 4; ++e) {
                    int n = nn[e], h = hv[e];
                    payload_n[hA[n >> SHIFT] + rn[k * 4 + e]] =
                        ((u32)(n & BMASK) << 17) | (u32)h;
                    payload_h[hB[h >> SHIFT] + rh[k * 4 + e]] =
                        ((u32)(h & BMASK) << 17) | (u32)n;
                }
            }
        }
    } else {
        // ---------------- gemm (grid-strided, register weights) ----------------
        float* wl = (float*)hA;                  // 384 floats of LDS
        if (t < 128) {                           // block-local W12 = W1@W2
            float a0 = 0.f, a1 = 0.f, a2 = 0.f;
            for (int m = 0; m < 64; ++m) {
                float ww = W1[t * 64 + m];
                a0 += ww * W2[m * 3 + 0];
                a1 += ww * W2[m * 3 + 1];
                a2 += ww * W2[m * 3 + 2];
            }
            wl[t * 3 + 0] = a0; wl[t * 3 + 1] = a1; wl[t * 3 + 2] = a2;
        }
        if (gemm_id == 0 && t < 3) {             // cvec = b1@W2 (read 2 dispatches later)
            float c = 0.f;
            for (int m = 0; m < 64; ++m) c += b1[m] * W2[m * 3 + t];
            cvec[t] = c;
        }
        __syncthreads();
        int grp = t >> 5, l = t & 31;            // 32 groups of 32 lanes
        float w0[4], w1[4], w2[4];
        #pragma unroll
        for (int i = 0; i < 4; ++i) {            // one-time LDS->reg copy
            int k = 4 * l + i;
            w0[i] = wl[k * 3 + 0];
            w1[i] = wl[k * 3 + 1];
            w2[i] = wl[k * 3 + 2];
        }
        for (int node = gemm_id * 32 + grp; node < N_NODES; node += NGRP) {
            float4 x4 = ((const float4*)(X + (size_t)node * IN_DIM))[l];
            float a0 = x4.x * w0[0] + x4.y * w0[1] + x4.z * w0[2] + x4.w * w0[3];
            float a1 = x4.x * w1[0] + x4.y * w1[1] + x4.z * w1[2] + x4.w * w1[3];
            float a2 = x4.x * w2[0] + x4.y * w2[1] + x4.z * w2[2] + x4.w * w2[3];
            #pragma unroll
            for (int off = 16; off > 0; off >>= 1) {
                a0 += __shfl_xor(a0, off);
                a1 += __shfl_xor(a1, off);
                a2 += __shfl_xor(a2, off);
            }
            if (l == 0) {
                Z[(size_t)node * 4 + 0] = a0;
                Z[(size_t)node * 4 + 1] = a1;
                Z[(size_t)node * 4 + 2] = a2;
                Z[(size_t)node * 4 + 3] = 0.f;
            }
        }
    }
}

// ---------------------------------------------------------------------------
// phase2 + gather1: block-per-bucket fine sort; hedge-direction blocks then
// immediately compute XeA[h] = Bmean(Z) for their 128 hedges (slots L2-warm).
__global__ void __launch_bounds__(256)
phase2_g1_kernel(const u32* __restrict__ payload_n, const u32* __restrict__ payload_h,
                 const u32* __restrict__ gcur, const float* __restrict__ Z,
                 u32* __restrict__ od_n, u32* __restrict__ od_h,
                 int* __restrict__ slot_n, int* __restrict__ slot_h,
                 float* __restrict__ XeA)
{
    __shared__ int hist[128], curs[128];
    int t = threadIdx.x;
    int bk = blockIdx.x;                          // 0..1563
    int dir = (bk >= NBKT) ? 1 : 0;
    int b = bk - dir * NBKT;
    const u32* payload = dir ? payload_h : payload_n;
    u32* od   = dir ? od_h   : od_n;
    int* slot = dir ? slot_h : slot_n;
    u32 g = gcur[b * 16];
    int tot = dir ? (int)(g >> 16) : (int)(g & 0xFFFFu);
    int base = b * CAP;

    if (t < 128) hist[t] = 0;
    __syncthreads();
    for (int j = t; j < tot; j += 256) atomicAdd(&hist[payload[base + j] >> 17], 1);
    __syncthreads();
    if (t < 64) {                                 // wave 0: scan 128 bins
        int lane = t;
        int h0 = hist[lane], h1 = hist[64 + lane];
        int s0 = h0, s1 = h1;
        #pragma unroll
        for (int d = 1; d < 64; d <<= 1) {
            int u0 = __shfl_up(s0, d), u1 = __shfl_up(s1, d);
            if (lane >= d) { s0 += u0; s1 += u1; }
        }
        int tot0 = __shfl(s0, 63);
        int e0 = s0 - h0, e1 = tot0 + s1 - h1;
        int d0 = (b << SHIFT) + lane, d1 = d0 + 64;
        if (d0 < N_NODES) od[d0] = ((u32)(base + e0) << 10) | (u32)h0;
        if (d1 < N_NODES) od[d1] = ((u32)(base + e1) << 10) | (u32)h1;
        curs[lane] = e0; curs[64 + lane] = e1;
    }
    __syncthreads();
    for (int j = t; j < tot; j += 256) {
        u32 p = payload[base + j];
        int r = atomicAdd(&curs[p >> 17], 1);
        slot[base + r] = (int)(p & 0x1FFFF);
    }
    if (!dir) return;

    // ---- gather1 for this bucket's 128 hedges (2 lanes per hedge) ----
    __syncthreads();
    int row = t >> 1, sub = t & 1;
    int h = (b << SHIFT) + row;
    if (h >= N_HEDGES) return;
    u32 v = od_h[h];                              // just written by this block (warm)
    int s = (int)(v >> 10), deg = (int)(v & 1023);
    float a0 = 0.f, a1 = 0.f, a2 = 0.f;
    for (int j = s + sub; j < s + deg; j += 2) {
        float4 x = ((const float4*)Z)[slot_h[j]];
        a0 += x.x; a1 += x.y; a2 += x.z;
    }
    a0 += __shfl_xor(a0, 1); a1 += __shfl_xor(a1, 1); a2 += __shfl_xor(a2, 1);
    if (sub == 0) {
        float inv = deg > 0 ? 1.0f / (float)deg : 0.f;
        ((float4*)XeA)[h] = make_float4(a0 * inv, a1 * inv, a2 * inv, 0.f);
    }
}

// ---------------------------------------------------------------------------
// oct-lane gather: 8 lanes per dest row; od = (start<<10)|deg
__global__ void gather_kernel(const float* __restrict__ src, float* __restrict__ dst,
                              const u32* __restrict__ od, const int* __restrict__ slot,
                              const float* __restrict__ addv, int nrows) {
    int tid = blockIdx.x * blockDim.x + threadIdx.x;
    int r = tid >> 3, sub = tid & 7;
    if (r >= nrows) return;
    u32 v = od[r];
    int s = (int)(v >> 10), deg = (int)(v & 1023);
    float a0 = 0.f, a1 = 0.f, a2 = 0.f;
    for (int j = s + sub; j < s + deg; j += 8) {
        float4 x = ((const float4*)src)[slot[j]];
        a0 += x.x; a1 += x.y; a2 += x.z;
    }
    a0 += __shfl_xor(a0, 1); a1 += __shfl_xor(a1, 1); a2 += __shfl_xor(a2, 1);
    a0 += __shfl_xor(a0, 2); a1 += __shfl_xor(a1, 2); a2 += __shfl_xor(a2, 2);
    a0 += __shfl_xor(a0, 4); a1 += __shfl_xor(a1, 4); a2 += __shfl_xor(a2, 4);
    if (sub == 0) {
        float inv = deg > 0 ? 1.0f / (float)deg : 0.f;
        float b0 = 0.f, b1 = 0.f, b2 = 0.f;
        if (addv) { b0 = addv[0]; b1 = addv[1]; b2 = addv[2]; }
        ((float4*)dst)[r] = make_float4(a0 * inv + b0, a1 * inv + b1, a2 * inv + b2, 0.f);
    }
}

// oct-lane hedge final: gather-mean of H2 -> sigmoid -> normalize -> gumbel -> argmax
__global__ void hedge_final_kernel(const float* __restrict__ H2,
                                   const u32* __restrict__ od_h, const int* __restrict__ slot_h,
                                   const float* __restrict__ gu, float* __restrict__ hard0,
                                   float* __restrict__ hard2, int n) {
    int tid = blockIdx.x * blockDim.x + threadIdx.x;
    int h = tid >> 3, sub = tid & 7;
    if (h >= n) return;
    u32 v = od_h[h];
    int s = (int)(v >> 10), deg = (int)(v & 1023);
    float a0 = 0.f, a1 = 0.f, a2 = 0.f;
    for (int j = s + sub; j < s + deg; j += 8) {
        float4 x = ((const float4*)H2)[slot_h[j]];
        a0 += x.x; a1 += x.y; a2 += x.z;
    }
    a0 += __shfl_xor(a0, 1); a1 += __shfl_xor(a1, 1); a2 += __shfl_xor(a2, 1);
    a0 += __shfl_xor(a0, 2); a1 += __shfl_xor(a1, 2); a2 += __shfl_xor(a2, 2);
    a0 += __shfl_xor(a0, 4); a1 += __shfl_xor(a1, 4); a2 += __shfl_xor(a2, 4);
    if (sub != 0) return;
    float binv = deg > 0 ? 1.0f / (float)deg : 0.f;
    float s0 = a0 * binv, s1 = a1 * binv, s2 = a2 * binv;
    float x0 = 1.0f / (1.0f + expf(-s0));
    float x1 = 1.0f / (1.0f + expf(-s1));
    float x2 = 1.0f / (1.0f + expf(-s2));
    float rs = x0 + x1 + x2;
    float rinv = rs != 0.f ? 1.0f / rs : 0.f;
    x0 *= rinv; x1 *= rinv; x2 *= rinv;
    const float EPS = 1e-10f;
    float g0 = -logf(-logf(gu[(size_t)h * 3 + 0] + EPS) + EPS);
    float g1 = -logf(-logf(gu[(size_t)h * 3 + 1] + EPS) + EPS);
    float g2 = -logf(-logf(gu[(size_t)h * 3 + 2] + EPS) + EPS);
    // argmax(softmax(x)) == argmax(x); first-max wins like jnp.argmax
    float v0 = x0 + g0, v1 = x1 + g1, v2 = x2 + g2;
    int am = 0; float vm = v0;
    if (v1 > vm) { am = 1; vm = v1; }
    if (v2 > vm) { am = 2; vm = v2; }
    hard0[h] = (am == 0) ? 1.f : 0.f;
    hard2[h] = (am == 2) ? 1.f : 0.f;
}

// per-incidence: sample + masked edge_index (int4 streams, float4 writes)
__global__ void edge_final_kernel(const float* __restrict__ hard0, const float* __restrict__ hard2,
                                  const float* __restrict__ ov,
                                  const int* __restrict__ ei0, const int* __restrict__ ei1,
                                  float* __restrict__ out, int n4) {
    int i4 = blockIdx.x * blockDim.x + threadIdx.x;
    if (i4 >= n4) return;
    int4 n4v = ((const int4*)ei0)[i4];
    int4 h4v = ((const int4*)ei1)[i4];
    int nn[4] = {n4v.x, n4v.y, n4v.z, n4v.w};
    int hh[4] = {h4v.x, h4v.y, h4v.z, h4v.w};
    float smp[4], oi[4], oh[4];
    #pragma unroll
    for (int e = 0; e < 4; ++e) {
        float r = hard0[hh[e]];
        float m = hard2[hh[e]] * (ov[nn[e]] < 0.5f ? 1.f : 0.f);
        float s = fmaxf(r, m);
        smp[e] = s;
        bool keep = s > 0.f;
        oi[e] = keep ? (float)nn[e] : -1.f;
        oh[e] = keep ? (float)hh[e] : -1.f;
    }
    ((float4*)out)[i4] = make_float4(smp[0], smp[1], smp[2], smp[3]);
    ((float4*)(out + N_INC))[i4] = make_float4(oi[0], oi[1], oi[2], oi[3]);
    ((float4*)(out + 2 * (size_t)N_INC))[i4] = make_float4(oh[0], oh[1], oh[2], oh[3]);
}

// ---------------------------------------------------------------------------
extern "C" void kernel_launch(void* const* d_in, const int* in_sizes, int n_in,
                              void* d_out, int out_size, void* d_ws, size_t ws_size,
                              hipStream_t stream) {
    const float* X  = (const float*)d_in[0];
    const float* W1 = (const float*)d_in[1];
    const float* b1 = (const float*)d_in[2];
    const float* W2 = (const float*)d_in[3];
    const float* b2 = (const float*)d_in[4];
    const float* ov = (const float*)d_in[5];
    const float* gu = (const float*)d_in[6];
    const int*   ei = (const int*)d_in[7];
    const int* ei0 = ei;            // nodes
    const int* ei1 = ei + N_INC;    // hedges

    // ---- workspace layout (int units; every section 16B-aligned) ----
    int* ip = (int*)d_ws;
    u32* gcur      = (u32*)ip;                    // 782 packed cursors, ×16 pad: 12512
    u32* payload_n = (u32*)(gcur + 12512);        // NBKT*CAP = 1601536
    u32* payload_h = payload_n + NBKT * CAP;      // 1601536
    int* slot_n    = (int*)(payload_h + NBKT * CAP); // 1601536
    int* slot_h    = slot_n + NBKT * CAP;         // 1601536
    u32* od_n      = (u32*)(slot_h + NBKT * CAP); // 100096
    u32* od_h      = od_n + 100096;               // 100096
    float* cvec    = (float*)(od_h + 100096);     // 16
    float* Z       = cvec + 16;                   // 400000
    float* XeA     = Z    + 4 * N_NODES;          // 400000
    float* XnA     = XeA  + 4 * N_HEDGES;         // 400000
    float* XeB     = XnA  + 4 * N_NODES;          // 400000
    float* XnB     = XeB  + 4 * N_HEDGES;         // 400000 (= H2)
    float* hard0   = XnB  + 4 * N_NODES;          // 100000
    float* hard2   = hard0 + N_HEDGES;            // 100000

    const int TB = 256;
    int gOct = (8 * N_NODES + TB - 1) / TB;       // 3125 (oct-lane row kernels)

    hipMemsetAsync(gcur, 0, 12512 * sizeof(u32), stream);
    fused_bg_kernel<<<GRID_BG, BT, 0, stream>>>(ei0, ei1, X, W1, b1, W2,
                                                gcur, payload_n, payload_h,
                                                cvec, Z);
    // phase2 + layer-1 hedge gather (XeA = Bmean(Z)) fused
    phase2_g1_kernel<<<2 * NBKT, 256, 0, stream>>>(payload_n, payload_h, gcur, Z,
                                                   od_n, od_h, slot_n, slot_h, XeA);

    gather_kernel<<<gOct, TB, 0, stream>>>(XeA, XnA, od_n, slot_n, cvec, N_NODES);
    // layer 2: H2 = mean_node(mean_hedge(XnA)) + b2
    gather_kernel<<<gOct, TB, 0, stream>>>(XnA, XeB, od_h, slot_h, nullptr, N_HEDGES);
    gather_kernel<<<gOct, TB, 0, stream>>>(XeB, XnB, od_n, slot_n, b2,      N_NODES);

    // scatter-mean of H2 into hedges fused with sigmoid/normalize/gumbel/argmax
    hedge_final_kernel<<<gOct, TB, 0, stream>>>(XnB, od_h, slot_h, gu, hard0, hard2, N_HEDGES);

    edge_final_kernel<<<(N_INC / 4 + TB - 1) / TB, TB, 0, stream>>>(hard0, hard2, ov, ei0, ei1,
                                                                    (float*)d_out, N_INC / 4);
}

// Round 18
// 111.426 us; speedup vs baseline: 1.0817x; 1.0817x over previous
//
#include <hip/hip_runtime.h>
#include <math.h>

#define N_NODES   100000
#define N_HEDGES  100000
#define N_INC     1000000
#define IN_DIM    128
#define SHIFT     7
#define BMASK     127
#define NBKT      782        // ceil(100000/128)
#define CAP       2048       // padded bucket capacity (max expected ~1500)
#define NBLK      245        // build chunks (1024 threads * 4 items)
#define GRID_BG   512        // fused grid: 256 build slots + 256 gemm slots
#define GEMM_TOT  267        // 256 + 11 surplus build slots
#define NGRP      (GEMM_TOT * 32)
#define BT        1024

typedef unsigned int u32;

// ---------------------------------------------------------------------------
// fused: XCD-aware role interleave — groups of 8 blocks alternate build/gemm
// so every XCD gets both roles co-resident (blk%8 = XCD id on MI355X).
// build: LDS histogram (register ranks) -> ONE packed dual-direction cursor
// fetch-add per bucket -> payload place. gemm: Z = X@W12, register weights.
__global__ void __launch_bounds__(BT)
fused_bg_kernel(const int* __restrict__ ei0, const int* __restrict__ ei1,
                const float* __restrict__ X, const float* __restrict__ W1,
                const float* __restrict__ b1, const float* __restrict__ W2,
                u32* __restrict__ gcur, u32* __restrict__ payload_n,
                u32* __restrict__ payload_h, float* __restrict__ cvec,
                float* __restrict__ Z)
{
    __shared__ int hA[NBKT], hB[NBKT];   // gemm branch reuses first 384 as floats
    int blk = blockIdx.x, t = threadIdx.x;

    int group = blk >> 3;                // 64 groups of 8 (one block per XCD)
    int inb   = blk & 7;
    bool is_build = (group & 1) == 0;
    int rid = (group >> 1) * 8 + inb;    // 0..255 within role
    int gemm_id = rid;
    if (is_build && rid >= NBLK) {       // surplus build slots -> extra gemm
        is_build = false;
        gemm_id = 256 + (rid - NBLK);
    }

    if (is_build) {
        // ---------------- build ----------------
        for (int i = t; i < NBKT; i += BT) { hA[i] = 0; hB[i] = 0; }
        __syncthreads();
        int i4 = rid * BT + t;                   // one int4 per thread
        bool ok = (i4 * 4 < N_INC);
        int4 n4 = ok ? ((const int4*)ei0)[i4] : make_int4(0, 0, 0, 0);
        int4 h4 = ok ? ((const int4*)ei1)[i4] : make_int4(0, 0, 0, 0);
        int nn[4] = {n4.x, n4.y, n4.z, n4.w};
        int hv[4] = {h4.x, h4.y, h4.z, h4.w};
        int rn[4], rh[4];
        if (ok) {
            #pragma unroll
            for (int e = 0; e < 4; ++e) {
                rn[e] = atomicAdd(&hA[nn[e] >> SHIFT], 1);   // rank = old count
                rh[e] = atomicAdd(&hB[hv[e] >> SHIFT], 1);
            }
        }
        __syncthreads();
        // exchange: ONE packed atomic reserves space in BOTH directions
        for (int i = t; i < NBKT; i += BT) {
            int cn = hA[i], ch = hB[i];
            if (cn | ch) {
                u32 old = atomicAdd(&gcur[i * 16], (u32)cn | ((u32)ch << 16));
                hA[i] = i * CAP + (int)(old & 0xFFFFu);
                hB[i] = i * CAP + (int)(old >> 16);
            }
        }
        __syncthreads();
        if (ok) {
            #pragma unroll
            for (int e = 0; e < 4; ++e) {
                int n = nn[e], h = hv[e];
                payload_n[hA[n >> SHIFT] + rn[e]] = ((u32)(n & BMASK) << 17) | (u32)h;
                payload_h[hB[h >> SHIFT] + rh[e]] = ((u32)(h & BMASK) << 17) | (u32)n;
            }
        }
    } else {
        // ---------------- gemm (grid-strided, register weights) ----------------
        float* wl = (float*)hA;                  // 384 floats of LDS
        if (t < 128) {                           // block-local W12 = W1@W2
            float a0 = 0.f, a1 = 0.f, a2 = 0.f;
            for (int m = 0; m < 64; ++m) {
                float ww = W1[t * 64 + m];
                a0 += ww * W2[m * 3 + 0];
                a1 += ww * W2[m * 3 + 1];
                a2 += ww * W2[m * 3 + 2];
            }
            wl[t * 3 + 0] = a0; wl[t * 3 + 1] = a1; wl[t * 3 + 2] = a2;
        }
        if (gemm_id == 0 && t < 3) {             // cvec = b1@W2 (read 2 dispatches later)
            float c = 0.f;
            for (int m = 0; m < 64; ++m) c += b1[m] * W2[m * 3 + t];
            cvec[t] = c;
        }
        __syncthreads();
        int grp = t >> 5, l = t & 31;            // 32 groups of 32 lanes
        float w0[4], w1[4], w2[4];
        #pragma unroll
        for (int i = 0; i < 4; ++i) {            // one-time LDS->reg copy
            int k = 4 * l + i;
            w0[i] = wl[k * 3 + 0];
            w1[i] = wl[k * 3 + 1];
            w2[i] = wl[k * 3 + 2];
        }
        for (int node = gemm_id * 32 + grp; node < N_NODES; node += NGRP) {
            float4 x4 = ((const float4*)(X + (size_t)node * IN_DIM))[l];
            float a0 = x4.x * w0[0] + x4.y * w0[1] + x4.z * w0[2] + x4.w * w0[3];
            float a1 = x4.x * w1[0] + x4.y * w1[1] + x4.z * w1[2] + x4.w * w1[3];
            float a2 = x4.x * w2[0] + x4.y * w2[1] + x4.z * w2[2] + x4.w * w2[3];
            #pragma unroll
            for (int off = 16; off > 0; off >>= 1) {
                a0 += __shfl_xor(a0, off);
                a1 += __shfl_xor(a1, off);
                a2 += __shfl_xor(a2, off);
            }
            if (l == 0) {
                Z[(size_t)node * 4 + 0] = a0;
                Z[(size_t)node * 4 + 1] = a1;
                Z[(size_t)node * 4 + 2] = a2;
                Z[(size_t)node * 4 + 3] = 0.f;
            }
        }
    }
}

// ---------------------------------------------------------------------------
// phase2 + gather1: block-per-bucket fine sort; hedge-direction blocks then
// immediately compute XeA[h] = Bmean(Z) for their 128 hedges (slots L2-warm).
__global__ void __launch_bounds__(256)
phase2_g1_kernel(const u32* __restrict__ payload_n, const u32* __restrict__ payload_h,
                 const u32* __restrict__ gcur, const float* __restrict__ Z,
                 u32* __restrict__ od_n, u32* __restrict__ od_h,
                 int* __restrict__ slot_n, int* __restrict__ slot_h,
                 float* __restrict__ XeA)
{
    __shared__ int hist[128], curs[128];
    int t = threadIdx.x;
    int bk = blockIdx.x;                          // 0..1563
    int dir = (bk >= NBKT) ? 1 : 0;
    int b = bk - dir * NBKT;
    const u32* payload = dir ? payload_h : payload_n;
    u32* od   = dir ? od_h   : od_n;
    int* slot = dir ? slot_h : slot_n;
    u32 g = gcur[b * 16];
    int tot = dir ? (int)(g >> 16) : (int)(g & 0xFFFFu);
    int base = b * CAP;

    if (t < 128) hist[t] = 0;
    __syncthreads();
    for (int j = t; j < tot; j += 256) atomicAdd(&hist[payload[base + j] >> 17], 1);
    __syncthreads();
    if (t < 64) {                                 // wave 0: scan 128 bins
        int lane = t;
        int h0 = hist[lane], h1 = hist[64 + lane];
        int s0 = h0, s1 = h1;
        #pragma unroll
        for (int d = 1; d < 64; d <<= 1) {
            int u0 = __shfl_up(s0, d), u1 = __shfl_up(s1, d);
            if (lane >= d) { s0 += u0; s1 += u1; }
        }
        int tot0 = __shfl(s0, 63);
        int e0 = s0 - h0, e1 = tot0 + s1 - h1;
        int d0 = (b << SHIFT) + lane, d1 = d0 + 64;
        if (d0 < N_NODES) od[d0] = ((u32)(base + e0) << 10) | (u32)h0;
        if (d1 < N_NODES) od[d1] = ((u32)(base + e1) << 10) | (u32)h1;
        curs[lane] = e0; curs[64 + lane] = e1;
    }
    __syncthreads();
    for (int j = t; j < tot; j += 256) {
        u32 p = payload[base + j];
        int r = atomicAdd(&curs[p >> 17], 1);
        slot[base + r] = (int)(p & 0x1FFFF);
    }
    if (!dir) return;

    // ---- gather1 for this bucket's 128 hedges (2 lanes per hedge) ----
    __syncthreads();
    int row = t >> 1, sub = t & 1;
    int h = (b << SHIFT) + row;
    if (h >= N_HEDGES) return;
    u32 v = od_h[h];                              // just written by this block (warm)
    int s = (int)(v >> 10), deg = (int)(v & 1023);
    float a0 = 0.f, a1 = 0.f, a2 = 0.f;
    for (int j = s + sub; j < s + deg; j += 2) {
        float4 x = ((const float4*)Z)[slot_h[j]];
        a0 += x.x; a1 += x.y; a2 += x.z;
    }
    a0 += __shfl_xor(a0, 1); a1 += __shfl_xor(a1, 1); a2 += __shfl_xor(a2, 1);
    if (sub == 0) {
        float inv = deg > 0 ? 1.0f / (float)deg : 0.f;
        ((float4*)XeA)[h] = make_float4(a0 * inv, a1 * inv, a2 * inv, 0.f);
    }
}

// ---------------------------------------------------------------------------
// oct-lane gather: 8 lanes per dest row; od = (start<<10)|deg
__global__ void gather_kernel(const float* __restrict__ src, float* __restrict__ dst,
                              const u32* __restrict__ od, const int* __restrict__ slot,
                              const float* __restrict__ addv, int nrows) {
    int tid = blockIdx.x * blockDim.x + threadIdx.x;
    int r = tid >> 3, sub = tid & 7;
    if (r >= nrows) return;
    u32 v = od[r];
    int s = (int)(v >> 10), deg = (int)(v & 1023);
    float a0 = 0.f, a1 = 0.f, a2 = 0.f;
    for (int j = s + sub; j < s + deg; j += 8) {
        float4 x = ((const float4*)src)[slot[j]];
        a0 += x.x; a1 += x.y; a2 += x.z;
    }
    a0 += __shfl_xor(a0, 1); a1 += __shfl_xor(a1, 1); a2 += __shfl_xor(a2, 1);
    a0 += __shfl_xor(a0, 2); a1 += __shfl_xor(a1, 2); a2 += __shfl_xor(a2, 2);
    a0 += __shfl_xor(a0, 4); a1 += __shfl_xor(a1, 4); a2 += __shfl_xor(a2, 4);
    if (sub == 0) {
        float inv = deg > 0 ? 1.0f / (float)deg : 0.f;
        float b0 = 0.f, b1 = 0.f, b2 = 0.f;
        if (addv) { b0 = addv[0]; b1 = addv[1]; b2 = addv[2]; }
        ((float4*)dst)[r] = make_float4(a0 * inv + b0, a1 * inv + b1, a2 * inv + b2, 0.f);
    }
}

// oct-lane hedge final: gather-mean of H2 -> sigmoid -> normalize -> gumbel -> argmax
__global__ void hedge_final_kernel(const float* __restrict__ H2,
                                   const u32* __restrict__ od_h, const int* __restrict__ slot_h,
                                   const float* __restrict__ gu, float* __restrict__ hard0,
                                   float* __restrict__ hard2, int n) {
    int tid = blockIdx.x * blockDim.x + threadIdx.x;
    int h = tid >> 3, sub = tid & 7;
    if (h >= n) return;
    u32 v = od_h[h];
    int s = (int)(v >> 10), deg = (int)(v & 1023);
    float a0 = 0.f, a1 = 0.f, a2 = 0.f;
    for (int j = s + sub; j < s + deg; j += 8) {
        float4 x = ((const float4*)H2)[slot_h[j]];
        a0 += x.x; a1 += x.y; a2 += x.z;
    }
    a0 += __shfl_xor(a0, 1); a1 += __shfl_xor(a1, 1); a2 += __shfl_xor(a2, 1);
    a0 += __shfl_xor(a0, 2); a1 += __shfl_xor(a1, 2); a2 += __shfl_xor(a2, 2);
    a0 += __shfl_xor(a0, 4); a1 += __shfl_xor(a1, 4); a2 += __shfl_xor(a2, 4);
    if (sub != 0) return;
    float binv = deg > 0 ? 1.0f / (float)deg : 0.f;
    float s0 = a0 * binv, s1 = a1 * binv, s2 = a2 * binv;
    float x0 = 1.0f / (1.0f + expf(-s0));
    float x1 = 1.0f / (1.0f + expf(-s1));
    float x2 = 1.0f / (1.0f + expf(-s2));
    float rs = x0 + x1 + x2;
    float rinv = rs != 0.f ? 1.0f / rs : 0.f;
    x0 *= rinv; x1 *= rinv; x2 *= rinv;
    const float EPS = 1e-10f;
    float g0 = -logf(-logf(gu[(size_t)h * 3 + 0] + EPS) + EPS);
    float g1 = -logf(-logf(gu[(size_t)h * 3 + 1] + EPS) + EPS);
    float g2 = -logf(-logf(gu[(size_t)h * 3 + 2] + EPS) + EPS);
    // argmax(softmax(x)) == argmax(x); first-max wins like jnp.argmax
    float v0 = x0 + g0, v1 = x1 + g1, v2 = x2 + g2;
    int am = 0; float vm = v0;
    if (v1 > vm) { am = 1; vm = v1; }
    if (v2 > vm) { am = 2; vm = v2; }
    hard0[h] = (am == 0) ? 1.f : 0.f;
    hard2[h] = (am == 2) ? 1.f : 0.f;
}

// per-incidence: sample + masked edge_index (int4 streams, float4 writes)
__global__ void edge_final_kernel(const float* __restrict__ hard0, const float* __restrict__ hard2,
                                  const float* __restrict__ ov,
                                  const int* __restrict__ ei0, const int* __restrict__ ei1,
                                  float* __restrict__ out, int n4) {
    int i4 = blockIdx.x * blockDim.x + threadIdx.x;
    if (i4 >= n4) return;
    int4 n4v = ((const int4*)ei0)[i4];
    int4 h4v = ((const int4*)ei1)[i4];
    int nn[4] = {n4v.x, n4v.y, n4v.z, n4v.w};
    int hh[4] = {h4v.x, h4v.y, h4v.z, h4v.w};
    float smp[4], oi[4], oh[4];
    #pragma unroll
    for (int e = 0; e < 4; ++e) {
        float r = hard0[hh[e]];
        float m = hard2[hh[e]] * (ov[nn[e]] < 0.5f ? 1.f : 0.f);
        float s = fmaxf(r, m);
        smp[e] = s;
        bool keep = s > 0.f;
        oi[e] = keep ? (float)nn[e] : -1.f;
        oh[e] = keep ? (float)hh[e] : -1.f;
    }
    ((float4*)out)[i4] = make_float4(smp[0], smp[1], smp[2], smp[3]);
    ((float4*)(out + N_INC))[i4] = make_float4(oi[0], oi[1], oi[2], oi[3]);
    ((float4*)(out + 2 * (size_t)N_INC))[i4] = make_float4(oh[0], oh[1], oh[2], oh[3]);
}

// ---------------------------------------------------------------------------
extern "C" void kernel_launch(void* const* d_in, const int* in_sizes, int n_in,
                              void* d_out, int out_size, void* d_ws, size_t ws_size,
                              hipStream_t stream) {
    const float* X  = (const float*)d_in[0];
    const float* W1 = (const float*)d_in[1];
    const float* b1 = (const float*)d_in[2];
    const float* W2 = (const float*)d_in[3];
    const float* b2 = (const float*)d_in[4];
    const float* ov = (const float*)d_in[5];
    const float* gu = (const float*)d_in[6];
    const int*   ei = (const int*)d_in[7];
    const int* ei0 = ei;            // nodes
    const int* ei1 = ei + N_INC;    // hedges

    // ---- workspace layout (int units; every section 16B-aligned) ----
    int* ip = (int*)d_ws;
    u32* gcur      = (u32*)ip;                    // 782 packed cursors, ×16 pad: 12512
    u32* payload_n = (u32*)(gcur + 12512);        // NBKT*CAP = 1601536
    u32* payload_h = payload_n + NBKT * CAP;      // 1601536
    int* slot_n    = (int*)(payload_h + NBKT * CAP); // 1601536
    int* slot_h    = slot_n + NBKT * CAP;         // 1601536
    u32* od_n      = (u32*)(slot_h + NBKT * CAP); // 100096
    u32* od_h      = od_n + 100096;               // 100096
    float* cvec    = (float*)(od_h + 100096);     // 16
    float* Z       = cvec + 16;                   // 400000
    float* XeA     = Z    + 4 * N_NODES;          // 400000
    float* XnA     = XeA  + 4 * N_HEDGES;         // 400000
    float* XeB     = XnA  + 4 * N_NODES;          // 400000
    float* XnB     = XeB  + 4 * N_HEDGES;         // 400000 (= H2)
    float* hard0   = XnB  + 4 * N_NODES;          // 100000
    float* hard2   = hard0 + N_HEDGES;            // 100000

    const int TB = 256;
    int gOct = (8 * N_NODES + TB - 1) / TB;       // 3125 (oct-lane row kernels)

    hipMemsetAsync(gcur, 0, 12512 * sizeof(u32), stream);
    fused_bg_kernel<<<GRID_BG, BT, 0, stream>>>(ei0, ei1, X, W1, b1, W2,
                                                gcur, payload_n, payload_h,
                                                cvec, Z);
    // phase2 + layer-1 hedge gather (XeA = Bmean(Z)) fused
    phase2_g1_kernel<<<2 * NBKT, 256, 0, stream>>>(payload_n, payload_h, gcur, Z,
                                                   od_n, od_h, slot_n, slot_h, XeA);

    gather_kernel<<<gOct, TB, 0, stream>>>(XeA, XnA, od_n, slot_n, cvec, N_NODES);
    // layer 2: H2 = mean_node(mean_hedge(XnA)) + b2
    gather_kernel<<<gOct, TB, 0, stream>>>(XnA, XeB, od_h, slot_h, nullptr, N_HEDGES);
    gather_kernel<<<gOct, TB, 0, stream>>>(XeB, XnB, od_n, slot_n, b2,      N_NODES);

    // scatter-mean of H2 into hedges fused with sigmoid/normalize/gumbel/argmax
    hedge_final_kernel<<<gOct, TB, 0, stream>>>(XnB, od_h, slot_h, gu, hard0, hard2, N_HEDGES);

    edge_final_kernel<<<(N_INC / 4 + TB - 1) / TB, TB, 0, stream>>>(hard0, hard2, ov, ei0, ei1,
                                                                    (float*)d_out, N_INC / 4);
}